// Round 1
// baseline (201.034 us; speedup 1.0000x reference)
//
#include <hip/hip_runtime.h>

// B=262144 batches; per batch solve min ||A w - r||, A=[-x1,-x2,-x3,1] (32x4), r=x0.
// Normal equations via 13 running sums + 4x4 Cholesky.
// R4: barrier-free per-wave double-buffered pipeline.
//   - Waves never share LDS data -> __syncthreads() removed entirely.
//   - Each wave owns 2 x 8 KiB buffers and processes 4 consecutive tiles
//     (16 batches each, 64 batches total), prefetching tile i+1 while
//     computing tile i with counted s_waitcnt vmcnt(8) (never 0 mid-loop).
//   - 64 KiB LDS/block -> 2 blocks/CU (8 waves/CU); in-flight = 8 KiB/wave,
//     ~64 KiB/CU >> ~10 KiB BW*latency product -> HBM stays saturated.
//   - 1024 blocks (vs 4096): 4x less block-turnover dead time.
// Per-tile compute unchanged from R3: 4 lanes per batch (8 rows each, rotated
// for conflict-free b128), DPP quad shfl_xor combine, redundant solve,
// lane0-of-quad stores.

#define GLOBAL_AS __attribute__((address_space(1)))
#define LDS_AS    __attribute__((address_space(3)))

__device__ __forceinline__ void async_copy16(const float4* gptr, float4* lptr) {
    __builtin_amdgcn_global_load_lds((const GLOBAL_AS void*)gptr,
                                     (LDS_AS void*)lptr, 16, 0, 0);
}

// Stage one 8 KiB tile (16 batches = 512 float4) into this wave's LDS buffer.
// 8 issues of 64 lanes x 16 B; LDS dst is wave-uniform base (+ lane*16 in HW).
__device__ __forceinline__ void stage_tile(const float4* src, float4* dst, int t) {
#pragma unroll
    for (int k = 0; k < 8; ++k) {
        async_copy16(src + k * 64 + t, dst + k * 64);
    }
}

// Solve 16 batches from one staged tile. Quad g = t>>2 owns batch (b0+g);
// sub = t&3 covers rows m = sub*8 + j, row order rotated by g so the wave's
// 64 b128 reads spread across all 8 LDS bank groups each step.
__device__ __forceinline__ void solve_tile(const float4* chunk, int g, int sub,
                                           int b, float* __restrict__ out) {
    float s11 = 0.f, s12 = 0.f, s13 = 0.f, s22 = 0.f, s23 = 0.f, s33 = 0.f;
    float s1 = 0.f, s2 = 0.f, s3 = 0.f;
    float t1 = 0.f, t2 = 0.f, t3 = 0.f, t0 = 0.f;

#pragma unroll
    for (int j = 0; j < 8; ++j) {
        int jj = (j + g) & 7;
        float4 v = chunk[g * 32 + sub * 8 + jj];
        float r  = v.x;
        float a1 = v.y, a2 = v.z, a3 = v.w;
        s11 = fmaf(a1, a1, s11);
        s12 = fmaf(a1, a2, s12);
        s13 = fmaf(a1, a3, s13);
        s22 = fmaf(a2, a2, s22);
        s23 = fmaf(a2, a3, s23);
        s33 = fmaf(a3, a3, s33);
        s1 += a1; s2 += a2; s3 += a3;
        t1 = fmaf(a1, r, t1);
        t2 = fmaf(a2, r, t2);
        t3 = fmaf(a3, r, t3);
        t0 += r;
    }

    // Combine the 4 partial sums within each quad (xor 1, xor 2 -> DPP).
#define QUAD_REDUCE(v) \
    v += __shfl_xor(v, 1); \
    v += __shfl_xor(v, 2);
    QUAD_REDUCE(s11) QUAD_REDUCE(s12) QUAD_REDUCE(s13)
    QUAD_REDUCE(s22) QUAD_REDUCE(s23) QUAD_REDUCE(s33)
    QUAD_REDUCE(s1)  QUAD_REDUCE(s2)  QUAD_REDUCE(s3)
    QUAD_REDUCE(t1)  QUAD_REDUCE(t2)  QUAD_REDUCE(t3)
    QUAD_REDUCE(t0)
#undef QUAD_REDUCE

    // Gram matrix G = A^T A, rhs = A^T r. All 4 lanes of the quad solve
    // redundantly (no divergence); lane sub==0 stores.
    float G[4][4];
    G[0][0] = s11; G[0][1] = s12; G[0][2] = s13; G[0][3] = -s1;
    G[1][0] = s12; G[1][1] = s22; G[1][2] = s23; G[1][3] = -s2;
    G[2][0] = s13; G[2][1] = s23; G[2][2] = s33; G[2][3] = -s3;
    G[3][0] = -s1; G[3][1] = -s2; G[3][2] = -s3; G[3][3] = 32.0f;
    float rhs[4] = { -t1, -t2, -t3, t0 };

    float L[4][4];
#pragma unroll
    for (int k = 0; k < 4; ++k) {
        float d = G[k][k];
#pragma unroll
        for (int j = 0; j < 4; ++j) {
            if (j < k) d = fmaf(-L[k][j], L[k][j], d);
        }
        float lkk = sqrtf(fmaxf(d, 1e-30f));
        L[k][k] = lkk;
        float inv = __frcp_rn(lkk);
#pragma unroll
        for (int i = 0; i < 4; ++i) {
            if (i > k) {
                float s = G[i][k];
#pragma unroll
                for (int j = 0; j < 4; ++j) {
                    if (j < k) s = fmaf(-L[i][j], L[k][j], s);
                }
                L[i][k] = s * inv;
            }
        }
    }

    float y[4];
#pragma unroll
    for (int i = 0; i < 4; ++i) {
        float s = rhs[i];
#pragma unroll
        for (int j = 0; j < 4; ++j) {
            if (j < i) s = fmaf(-L[i][j], y[j], s);
        }
        y[i] = s * __frcp_rn(L[i][i]);
    }

    float wv[4];
#pragma unroll
    for (int i = 3; i >= 0; --i) {
        float s = y[i];
#pragma unroll
        for (int j = 0; j < 4; ++j) {
            if (j > i) s = fmaf(-L[j][i], wv[j], s);
        }
        wv[i] = s * __frcp_rn(L[i][i]);
    }

    if (sub == 0) {
        reinterpret_cast<float4*>(out)[b] = make_float4(wv[0], wv[1], wv[2], wv[3]);
    }
}

#define WAIT_VMCNT_8() do {                                   \
        asm volatile("s_waitcnt vmcnt(8)" ::: "memory");      \
        __builtin_amdgcn_sched_barrier(0);                    \
    } while (0)
#define WAIT_VMCNT_0() do {                                   \
        asm volatile("s_waitcnt vmcnt(0)" ::: "memory");      \
        __builtin_amdgcn_sched_barrier(0);                    \
    } while (0)

__global__ __launch_bounds__(256) void basicls_kernel(const float* __restrict__ x,
                                                      float* __restrict__ out) {
    // 4 waves x 2 buffers x 512 float4 (8 KiB) = 64 KiB per block.
    __shared__ float4 tile[4 * 2 * 512];

    const int tid = threadIdx.x;
    const int w   = tid >> 6;          // wave 0..3 (wave-uniform)
    const int t   = tid & 63;          // lane 0..63
    const int g   = t >> 2;
    const int sub = t & 3;

    const int wgid = blockIdx.x * 4 + w;               // global wave id 0..4095
    const float4* src = reinterpret_cast<const float4*>(x) + (size_t)wgid * 2048;
    const int bbase = wgid * 64;                       // 64 batches per wave

    float4* buf0 = tile + w * 1024;
    float4* buf1 = buf0 + 512;

    // Prologue: stage tile 0.
    stage_tile(src, buf0, t);

    // i=0: prefetch tile 1, wait for tile 0 (8 newest = tile-1 loads stay
    //      in flight), compute tile 0.
    stage_tile(src + 512, buf1, t);
    WAIT_VMCNT_8();
    solve_tile(buf0, g, sub, bbase + g, out);

    // i=1: prefetch tile 2 into buf0, wait drains tile-1 loads (and the
    //      older tile-0 store), compute tile 1.
    stage_tile(src + 1024, buf0, t);
    WAIT_VMCNT_8();
    solve_tile(buf1, g, sub, bbase + 16 + g, out);

    // i=2: prefetch tile 3 into buf1, compute tile 2.
    stage_tile(src + 1536, buf1, t);
    WAIT_VMCNT_8();
    solve_tile(buf0, g, sub, bbase + 32 + g, out);

    // i=3: tail — drain everything, compute tile 3.
    WAIT_VMCNT_0();
    solve_tile(buf1, g, sub, bbase + 48 + g, out);
}

extern "C" void kernel_launch(void* const* d_in, const int* in_sizes, int n_in,
                              void* d_out, int out_size, void* d_ws, size_t ws_size,
                              hipStream_t stream) {
    const float* x = (const float*)d_in[0];
    // d_in[1] = pad_mask: unused by the reference computation.
    float* out = (float*)d_out;
    int B = in_sizes[0] / (32 * 4);        // 262144
    dim3 block(256);
    dim3 grid(B / 256);                    // 1024 blocks, 256 batches each
    basicls_kernel<<<grid, block, 0, stream>>>(x, out);
}